// Round 6
// baseline (335.701 us; speedup 1.0000x reference)
//
#include <hip/hip_runtime.h>

#define BATCH 262144
#define EMB 300
#define NBUCK 8192          // ci>>4 : max 6249 < 8192
#define BSHIFT 4
#define NBLK 4096
#define WPB 4
#define PPW 16
#define UNROLL 4

// ---------------- sort phase ----------------

__global__ __launch_bounds__(1024) void glove_zero_counts(int* __restrict__ counts) {
    const int i = blockIdx.x * 1024 + threadIdx.x;
    if (i < NBUCK) counts[i] = 0;
}

__global__ __launch_bounds__(256) void glove_hist(
    const int* __restrict__ center, int* __restrict__ counts)
{
    const int i = blockIdx.x * 256 + threadIdx.x;
    const int stride = gridDim.x * 256;
    for (int p = i; p < BATCH; p += stride)
        atomicAdd(&counts[center[p] >> BSHIFT], 1);
}

__global__ __launch_bounds__(1024) void glove_scan(
    const int* __restrict__ counts, int* __restrict__ cursors)
{
    __shared__ int sums[1024];
    const int t = threadIdx.x;
    int local[8];
    int s = 0;
    #pragma unroll
    for (int i = 0; i < 8; ++i) { local[i] = counts[t * 8 + i]; s += local[i]; }
    sums[t] = s;
    __syncthreads();
    for (int off = 1; off < 1024; off <<= 1) {
        int v = (t >= off) ? sums[t - off] : 0;
        __syncthreads();
        sums[t] += v;
        __syncthreads();
    }
    int excl = (t == 0) ? 0 : sums[t - 1];
    #pragma unroll
    for (int i = 0; i < 8; ++i) { cursors[t * 8 + i] = excl; excl += local[i]; }
}

__global__ __launch_bounds__(256) void glove_scatter(
    const int*   __restrict__ center,
    const int*   __restrict__ outside,
    const float* __restrict__ coocs,
    const float* __restrict__ weighting,
    int* __restrict__ cursors,
    int4* __restrict__ sorted)
{
    const int i = blockIdx.x * 256 + threadIdx.x;
    const int stride = gridDim.x * 256;
    for (int p = i; p < BATCH; p += stride) {
        const int ci = center[p];
        int4 rec;
        rec.x = ci;
        rec.y = outside[p];
        rec.z = __float_as_int(coocs[p]);
        rec.w = __float_as_int(weighting[p]);
        const int pos = atomicAdd(&cursors[ci >> BSHIFT], 1);
        sorted[pos] = rec;
    }
}

// ---------------- gather phase (round-2 structure, sorted input) ----------------

__global__ __launch_bounds__(256) void glove_main_sorted(
    const int4*  __restrict__ sorted,
    const float* __restrict__ cemb,
    const float* __restrict__ oemb,
    const float* __restrict__ cbias,
    const float* __restrict__ obias,
    float*       __restrict__ block_sums)
{
    const int lane = threadIdx.x & 63;
    const int warp = threadIdx.x >> 6;
    const int wave_base = (blockIdx.x * WPB + warp) * PPW;

    float local = 0.0f;

    #pragma unroll
    for (int it = 0; it < PPW / UNROLL; ++it) {
        const int p0 = wave_base + it * UNROLL;

        int   ci[UNROLL], oi[UNROLL];
        float cb[UNROLL], ob2[UNROLL], cc[UNROLL], wt[UNROLL];
        float acc[UNROLL];

        #pragma unroll
        for (int j = 0; j < UNROLL; ++j) {
            int4 rec = sorted[p0 + j];
            ci[j] = rec.x;
            oi[j] = rec.y;
            cc[j] = __int_as_float(rec.z);
            wt[j] = __int_as_float(rec.w);
        }
        #pragma unroll
        for (int j = 0; j < UNROLL; ++j) {
            cb[j]  = cbias[ci[j]];
            ob2[j] = obias[oi[j]];
        }
        #pragma unroll
        for (int j = 0; j < UNROLL; ++j) {
            const float4* __restrict__ A = (const float4*)(cemb + (long)ci[j] * EMB);
            const float4* __restrict__ B = (const float4*)(oemb + (long)oi[j] * EMB);
            float4 a = A[lane];
            float4 b = B[lane];
            float s = a.x * b.x + a.y * b.y + a.z * b.z + a.w * b.w;
            if (lane < 11) {                  // 75 float4/row: lanes 0..10 cover [64,75)
                float4 a2 = A[lane + 64];
                float4 b2 = B[lane + 64];
                s += a2.x * b2.x + a2.y * b2.y + a2.z * b2.z + a2.w * b2.w;
            }
            acc[j] = s;
        }
        #pragma unroll
        for (int off = 32; off > 0; off >>= 1) {
            #pragma unroll
            for (int j = 0; j < UNROLL; ++j)
                acc[j] += __shfl_down(acc[j], off, 64);
        }
        if (lane == 0) {
            #pragma unroll
            for (int j = 0; j < UNROLL; ++j) {
                const float e = acc[j] + cb[j] + ob2[j] - cc[j];
                local += wt[j] * e * e;
            }
        }
    }

    __shared__ float smem[WPB];
    if (lane == 0) smem[warp] = local;
    __syncthreads();
    if (threadIdx.x == 0)
        block_sums[blockIdx.x] = smem[0] + smem[1] + smem[2] + smem[3];
}

// fallback: direct (unsorted) path, used only if ws too small
__global__ __launch_bounds__(256) void glove_main_direct(
    const int*   __restrict__ center,
    const int*   __restrict__ outside,
    const float* __restrict__ coocs,
    const float* __restrict__ weighting,
    const float* __restrict__ cemb,
    const float* __restrict__ oemb,
    const float* __restrict__ cbias,
    const float* __restrict__ obias,
    float*       __restrict__ block_sums)
{
    const int lane = threadIdx.x & 63;
    const int warp = threadIdx.x >> 6;
    const int wave_base = (blockIdx.x * WPB + warp) * PPW;

    float local = 0.0f;

    #pragma unroll
    for (int it = 0; it < PPW / UNROLL; ++it) {
        const int p0 = wave_base + it * UNROLL;
        int   ci[UNROLL], oi[UNROLL];
        float cb[UNROLL], ob2[UNROLL], cc[UNROLL], wt[UNROLL];
        float acc[UNROLL];
        #pragma unroll
        for (int j = 0; j < UNROLL; ++j) { ci[j] = center[p0+j]; oi[j] = outside[p0+j]; }
        #pragma unroll
        for (int j = 0; j < UNROLL; ++j) {
            cc[j] = coocs[p0+j]; wt[j] = weighting[p0+j];
            cb[j] = cbias[ci[j]]; ob2[j] = obias[oi[j]];
        }
        #pragma unroll
        for (int j = 0; j < UNROLL; ++j) {
            const float4* __restrict__ A = (const float4*)(cemb + (long)ci[j] * EMB);
            const float4* __restrict__ B = (const float4*)(oemb + (long)oi[j] * EMB);
            float4 a = A[lane]; float4 b = B[lane];
            float s = a.x*b.x + a.y*b.y + a.z*b.z + a.w*b.w;
            if (lane < 11) {
                float4 a2 = A[lane+64]; float4 b2 = B[lane+64];
                s += a2.x*b2.x + a2.y*b2.y + a2.z*b2.z + a2.w*b2.w;
            }
            acc[j] = s;
        }
        #pragma unroll
        for (int off = 32; off > 0; off >>= 1)
            #pragma unroll
            for (int j = 0; j < UNROLL; ++j)
                acc[j] += __shfl_down(acc[j], off, 64);
        if (lane == 0)
            #pragma unroll
            for (int j = 0; j < UNROLL; ++j) {
                const float e = acc[j] + cb[j] + ob2[j] - cc[j];
                local += wt[j] * e * e;
            }
    }

    __shared__ float smem[WPB];
    if (lane == 0) smem[warp] = local;
    __syncthreads();
    if (threadIdx.x == 0)
        block_sums[blockIdx.x] = smem[0] + smem[1] + smem[2] + smem[3];
}

__global__ __launch_bounds__(1024) void glove_reduce(
    const float* __restrict__ part, float* __restrict__ out)
{
    const int t = threadIdx.x;
    float4 v = ((const float4*)part)[t];          // 1024 x 4 = 4096 partials
    float s = v.x + v.y + v.z + v.w;
    #pragma unroll
    for (int off = 32; off > 0; off >>= 1)
        s += __shfl_down(s, off, 64);
    __shared__ float sm[16];
    if ((t & 63) == 0) sm[t >> 6] = s;
    __syncthreads();
    if (t < 16) {
        float x = sm[t];
        #pragma unroll
        for (int off = 8; off > 0; off >>= 1)
            x += __shfl_down(x, off, 16);
        if (t == 0) out[0] = x;
    }
}

extern "C" void kernel_launch(void* const* d_in, const int* in_sizes, int n_in,
                              void* d_out, int out_size, void* d_ws, size_t ws_size,
                              hipStream_t stream) {
    const int*   center    = (const int*)  d_in[0];
    const int*   outside   = (const int*)  d_in[1];
    const float* coocs     = (const float*)d_in[2];
    const float* weighting = (const float*)d_in[3];
    const float* cemb      = (const float*)d_in[4];
    const float* oemb      = (const float*)d_in[5];
    const float* cbias     = (const float*)d_in[6];
    const float* obias     = (const float*)d_in[7];
    float* out = (float*)d_out;

    char* ws = (char*)d_ws;
    const size_t off_counts  = 0;
    const size_t off_cursors = off_counts  + (size_t)NBUCK * 4;            // 32 KB
    const size_t off_sorted  = off_cursors + (size_t)NBUCK * 4;            // 64 KB
    const size_t off_bsums   = off_sorted  + (size_t)BATCH * 16;           // 64 KB + 4 MB
    const size_t need        = off_bsums   + (size_t)NBLK * 4;

    if (ws_size >= need) {
        int*  counts  = (int*) (ws + off_counts);
        int*  cursors = (int*) (ws + off_cursors);
        int4* sorted  = (int4*)(ws + off_sorted);
        float* bsums  = (float*)(ws + off_bsums);

        glove_zero_counts<<<(NBUCK + 1023) / 1024, 1024, 0, stream>>>(counts);
        glove_hist<<<256, 256, 0, stream>>>(center, counts);
        glove_scan<<<1, 1024, 0, stream>>>(counts, cursors);
        glove_scatter<<<256, 256, 0, stream>>>(center, outside, coocs, weighting,
                                               cursors, sorted);
        glove_main_sorted<<<NBLK, 256, 0, stream>>>(sorted, cemb, oemb, cbias, obias,
                                                    bsums);
        glove_reduce<<<1, 1024, 0, stream>>>(bsums, out);
    } else {
        float* bsums = (float*)ws;   // NBLK floats = 16 KB
        glove_main_direct<<<NBLK, 256, 0, stream>>>(
            center, outside, coocs, weighting, cemb, oemb, cbias, obias, bsums);
        glove_reduce<<<1, 1024, 0, stream>>>(bsums, out);
    }
}

// Round 8
// 311.107 us; speedup vs baseline: 1.0791x; 1.0791x over previous
//
#include <hip/hip_runtime.h>

#define BATCH 262144
#define EMB 300
#define NBLK 4096      // 4096 blocks x 4 waves x 16 pairs = 262144 pairs

__global__ __launch_bounds__(256) void glove_main(
    const int*   __restrict__ center,
    const int*   __restrict__ outside,
    const float* __restrict__ coocs,
    const float* __restrict__ weighting,
    const float* __restrict__ cemb,
    const float* __restrict__ oemb,
    const float* __restrict__ cbias,
    const float* __restrict__ obias,
    float*       __restrict__ block_sums)
{
    const int tid  = threadIdx.x;
    const int warp = tid >> 6;
    const int lane = tid & 63;
    const int l4   = lane & 3;        // lane within quad
    const int pg   = lane >> 2;       // pair-group 0..15
    const int p    = (blockIdx.x * 4 + warp) * 16 + pg;   // one pair per quad

    const int   ci = center[p];
    const int   oi = outside[p];
    const float cc = coocs[p];
    const float wt = weighting[p];
    const float cb = cbias[ci];       // issues early, consumed at the end
    const float ob = obias[oi];

    // single base address per row; 18 loads each with immediate offsets
    const float4* __restrict__ A = (const float4*)(cemb + (long)ci * EMB);
    const float4* __restrict__ B = (const float4*)(oemb + (long)oi * EMB);

    float acc = 0.0f;
    #pragma unroll
    for (int k = 0; k < 18; ++k) {    // quad covers float4 idx l4+4k : 0..71
        float4 a = A[l4 + 4 * k];
        float4 b = B[l4 + 4 * k];
        acc += a.x * b.x + a.y * b.y + a.z * b.z + a.w * b.w;
    }
    if (l4 < 3) {                     // tail: idx 72,73,74
        float4 a = A[72 + l4];
        float4 b = B[72 + l4];
        acc += a.x * b.x + a.y * b.y + a.z * b.z + a.w * b.w;
    }

    // 2-step butterfly within the quad: full dot in every quad lane
    acc += __shfl_xor(acc, 1);
    acc += __shfl_xor(acc, 2);

    const float e = acc + cb + ob - cc;
    float local = (l4 == 0) ? wt * e * e : 0.0f;

    // one wave-wide reduction per wave (6 steps, amortized over 16 pairs)
    #pragma unroll
    for (int off = 32; off > 0; off >>= 1)
        local += __shfl_down(local, off, 64);

    __shared__ float smem[4];
    if (lane == 0) smem[warp] = local;
    __syncthreads();
    if (tid == 0)
        block_sums[blockIdx.x] = smem[0] + smem[1] + smem[2] + smem[3];
}

__global__ __launch_bounds__(1024) void glove_reduce(
    const float* __restrict__ part, float* __restrict__ out)
{
    const int t = threadIdx.x;
    float4 v = ((const float4*)part)[t];          // 1024 x 4 = 4096 partials
    float s = v.x + v.y + v.z + v.w;
    #pragma unroll
    for (int off = 32; off > 0; off >>= 1)
        s += __shfl_down(s, off, 64);
    __shared__ float sm[16];
    if ((t & 63) == 0) sm[t >> 6] = s;
    __syncthreads();
    if (t < 16) {
        float x = sm[t];
        #pragma unroll
        for (int off = 8; off > 0; off >>= 1)
            x += __shfl_down(x, off, 16);
        if (t == 0) out[0] = x;
    }
}

extern "C" void kernel_launch(void* const* d_in, const int* in_sizes, int n_in,
                              void* d_out, int out_size, void* d_ws, size_t ws_size,
                              hipStream_t stream) {
    const int*   center    = (const int*)  d_in[0];
    const int*   outside   = (const int*)  d_in[1];
    const float* coocs     = (const float*)d_in[2];
    const float* weighting = (const float*)d_in[3];
    const float* cemb      = (const float*)d_in[4];
    const float* oemb      = (const float*)d_in[5];
    const float* cbias     = (const float*)d_in[6];
    const float* obias     = (const float*)d_in[7];
    float* out        = (float*)d_out;
    float* block_sums = (float*)d_ws;   // NBLK floats = 16 KB, fully overwritten

    glove_main<<<NBLK, 256, 0, stream>>>(
        center, outside, coocs, weighting, cemb, oemb, cbias, obias, block_sums);
    glove_reduce<<<1, 1024, 0, stream>>>(block_sums, out);
}